// Round 1
// baseline (295.206 us; speedup 1.0000x reference)
//
#include <hip/hip_runtime.h>
#include <cmath>

// Problem constants (from reference)
#define NB 4
#define NP 8192          // 2^13 points per batch
#define NE 262144        // 2^18 edges per batch
#define NCIN 32
#define NCOUT 32
#define NH 16
#define GAMMA 4.0f

typedef _Float16 half8 __attribute__((ext_vector_type(8)));
typedef float floatx4 __attribute__((ext_vector_type(4)));

// GEMM view: msg[e, o] = sum_k Z[e,k] * W2T[k,o],  k = h*32 + i, K = 512
//   Z[e, h*32+i] = rbf_h(e) * x_src[e][i]
// MFMA f32_16x16x32_f16 layouts (HW-verified, learn_hip m89/m91):
//   A: lane holds A[m=lane&15][k_local = (lane>>4)*8 + j], j=0..7
//   B: lane holds B[k_local = (lane>>4)*8 + j][n = lane&15]
//   D: lane holds D[row=(lane>>4)*4 + r][col = lane&15], r=0..3
// Since k = s*32 + q*8 + j  =>  h = s, i = q*8+j: the A-frag is just
// rbf_s(edge m) * x_src[m][q*8 .. q*8+7] — built directly in registers.

__global__ __launch_bounds__(256, 4)
void pconv_mfma_kernel(const float* __restrict__ features,
                       const float* __restrict__ edge_vec,
                       const float* __restrict__ W,
                       const float* __restrict__ mu,
                       const int* __restrict__ edge_src,
                       const int* __restrict__ edge_dst,
                       const int* __restrict__ n_norm_p,
                       float* __restrict__ out,
                       int num_tiles)   // tiles of 64 edges (4 waves x 16)
{
    // W swizzled to exact B-fragment order:
    //   wsw[ ((s*2+u)*64 + lane)*8 + j ] = W[h=s][o=(lane&15)+16u][i=(lane>>4)*8+j]
    // so the K-loop B read is: consecutive lanes -> consecutive 16B (conflict-free b128)
    __shared__ _Float16 wsw[16 * 2 * 64 * 8];   // 32 KiB
    __shared__ float mus[16];

    const int tid = threadIdx.x;

    for (int idx = tid; idx < 16384; idx += 256) {
        int j = idx & 7;
        int l = (idx >> 3) & 63;
        int u = (idx >> 9) & 1;
        int s = idx >> 10;
        int n = (l & 15) + (u << 4);          // output channel o
        int i = ((l >> 4) << 3) | j;          // input channel
        wsw[idx] = (_Float16)W[(s * NCOUT + n) * NCIN + i];
    }
    if (tid < 16) mus[tid] = mu[tid];
    __syncthreads();

    const int lane = tid & 63;
    const int wv   = tid >> 6;
    const int m    = lane & 15;   // A-row (edge) in main loop; D-col (channel) in epilogue
    const int q    = lane >> 4;

    const int nn = n_norm_p[0];
    const float scale = (nn > 0) ? rsqrtf((float)nn) : 1.0f;

    for (long tile = blockIdx.x; tile < num_tiles; tile += gridDim.x) {
        const long ebase = tile * 64 + (long)wv * 16;   // this wave's 16 edges
        const long ge = ebase + m;
        const int  b  = (int)(ge >> 18);                // NE = 2^18
        const int  src = edge_src[ge];

        // gather this lane's 8-float slice of x_src (32B-aligned)
        const float* xrow = features + (((long)b << 13) + (long)src) * NCIN + q * 8;
        floatx4 xa = *(const floatx4*)(xrow);
        floatx4 xb = *(const floatx4*)(xrow + 4);

        const float* ev = edge_vec + ge * 3;
        float vx = ev[0], vy = ev[1], vz = ev[2];
        // self-interaction zeroing in ref is a no-op numerically (r<1e-10 -> r=0)
        float r = sqrtf(vx * vx + vy * vy + vz * vz);

        float rbf[16];
        #pragma unroll
        for (int s = 0; s < 16; ++s) {
            float d = r - mus[s];
            rbf[s] = __expf(-GAMMA * d * d);
        }

        floatx4 accLo = {0.f, 0.f, 0.f, 0.f};   // channels 0..15
        floatx4 accHi = {0.f, 0.f, 0.f, 0.f};   // channels 16..31

        #pragma unroll
        for (int s = 0; s < 16; ++s) {
            const float rb = rbf[s];
            half8 a;
            a[0] = (_Float16)(rb * xa[0]);
            a[1] = (_Float16)(rb * xa[1]);
            a[2] = (_Float16)(rb * xa[2]);
            a[3] = (_Float16)(rb * xa[3]);
            a[4] = (_Float16)(rb * xb[0]);
            a[5] = (_Float16)(rb * xb[1]);
            a[6] = (_Float16)(rb * xb[2]);
            a[7] = (_Float16)(rb * xb[3]);
            half8 b0 = *(const half8*)(wsw + ((s * 2 + 0) * 64 + lane) * 8);
            half8 b1 = *(const half8*)(wsw + ((s * 2 + 1) * 64 + lane) * 8);
            accLo = __builtin_amdgcn_mfma_f32_16x16x32_f16(a, b0, accLo, 0, 0, 0);
            accHi = __builtin_amdgcn_mfma_f32_16x16x32_f16(a, b1, accHi, 0, 0, 0);
        }

        // Epilogue: lane holds D[row = q*4+r][col = m]; row = edge within tile.
        // 16 lanes (same q,r) cover 16 consecutive channels -> coalesced atomics.
        #pragma unroll
        for (int rr = 0; rr < 4; ++rr) {
            const long e2  = ebase + q * 4 + rr;
            const int  b2  = (int)(e2 >> 18);
            const int  dst = edge_dst[e2];
            float* orow = out + (((long)b2 << 13) + (long)dst) * NCOUT;
            atomicAdd(orow + m,      accLo[rr] * scale);
            atomicAdd(orow + m + 16, accHi[rr] * scale);
        }
    }
}

extern "C" void kernel_launch(void* const* d_in, const int* in_sizes, int n_in,
                              void* d_out, int out_size, void* d_ws, size_t ws_size,
                              hipStream_t stream) {
    const float* features = (const float*)d_in[0];
    const float* edge_vec = (const float*)d_in[1];
    const float* W        = (const float*)d_in[2];
    const float* mu       = (const float*)d_in[3];
    const int*   edge_src = (const int*)d_in[4];
    const int*   edge_dst = (const int*)d_in[5];
    const int*   n_norm   = (const int*)d_in[6];
    float* out = (float*)d_out;

    // harness poisons d_out with 0xAA before every launch; we accumulate via atomics
    hipMemsetAsync(out, 0, (size_t)out_size * sizeof(float), stream);

    const int num_tiles = (NB * NE) / 64;   // 16384 tiles of 64 edges
    const int grid = 1024;                  // 4 blocks/CU (LDS 32KB -> fits), grid-stride
    pconv_mfma_kernel<<<grid, 256, 0, stream>>>(features, edge_vec, W, mu,
                                                edge_src, edge_dst, n_norm,
                                                out, num_tiles);
}